// Round 5
// baseline (4203.834 us; speedup 1.0000x reference)
//
#include <hip/hip_runtime.h>

constexpr int C_NTOK = 4096;   // B*S
constexpr int C_DIM  = 1024;
constexpr int C_NL   = 8;
constexpr int C_NH   = 16;
constexpr int C_NKVH = 8;
constexpr int C_FF   = 4096;
constexpr int C_HD   = 64;
constexpr int C_B    = 2;
constexpr int C_S    = 2048;
constexpr int C_V    = 4054;
constexpr int C_PAD  = 4053;

typedef unsigned short u16;
typedef unsigned int   u32;
typedef __attribute__((ext_vector_type(4))) float f32x4;
typedef __attribute__((ext_vector_type(8))) short s16x8;

__device__ __forceinline__ float bf2f(u16 u) {
  u32 i = ((u32)u) << 16; float f; __builtin_memcpy(&f, &i, 4); return f;
}
__device__ __forceinline__ u16 f2bf(float f) {
  u32 i; __builtin_memcpy(&i, &f, 4);
  return (u16)((i + 0x7FFFu + ((i >> 16) & 1u)) >> 16);   // RNE
}
__device__ __forceinline__ f32x4 mfma16(s16x8 a, s16x8 b, f32x4 c) {
  return __builtin_amdgcn_mfma_f32_16x16x32_bf16(a, b, c, 0, 0, 0);
}
__device__ __forceinline__ void gld16(const void* g, void* l) {
  __builtin_amdgcn_global_load_lds((const __attribute__((address_space(1))) unsigned int*)g,
                                   (__attribute__((address_space(3))) unsigned int*)l, 16, 0, 0);
}

// ---------------- embedding gather ----------------
__global__ __launch_bounds__(256) void k_embed(const int* __restrict__ ids,
                                               const float* __restrict__ emb,
                                               float* __restrict__ x) {
  int t = blockIdx.x;
  const float4* src = (const float4*)(emb + (size_t)ids[t] * C_DIM);
  float4* dst = (float4*)(x + (size_t)t * C_DIM);
  dst[threadIdx.x] = src[threadIdx.x];
}

// ---------------- pad-key bias ----------------
__global__ void k_bias(const int* __restrict__ ids, float* __restrict__ bias) {
  int i = blockIdx.x * 256 + threadIdx.x;
  if (i < C_NTOK) bias[i] = (ids[i] == C_PAD) ? -1e30f : 0.0f;
}

// ---------------- rmsnorm: fp32 row -> bf16 row ----------------
__global__ __launch_bounds__(256) void k_rmsnorm(const float* __restrict__ x,
                                                 const float* __restrict__ w,
                                                 u16* __restrict__ out) {
  int row = blockIdx.x, tid = threadIdx.x;
  float4 v = ((const float4*)(x + (size_t)row * C_DIM))[tid];
  float ss = v.x * v.x + v.y * v.y + v.z * v.z + v.w * v.w;
#pragma unroll
  for (int d = 1; d < 64; d <<= 1) ss += __shfl_xor(ss, d, 64);
  __shared__ float sm[4];
  if ((tid & 63) == 0) sm[tid >> 6] = ss;
  __syncthreads();
  float tot = sm[0] + sm[1] + sm[2] + sm[3];
  float rs = 1.0f / sqrtf(tot * (1.0f / C_DIM) + 1e-5f);
  float4 wv = ((const float4*)w)[tid];
  uint2 o;
  o.x = (u32)f2bf(v.x * rs * wv.x) | ((u32)f2bf(v.y * rs * wv.y) << 16);
  o.y = (u32)f2bf(v.z * rs * wv.z) | ((u32)f2bf(v.w * rs * wv.w) << 16);
  ((uint2*)(out + (size_t)row * C_DIM))[tid] = o;
}

// ---------------- weight transpose-convert: W[K,N] f32 -> Wt[Npad,K] bf16 ----------------
__global__ __launch_bounds__(256) void k_wT(const float* __restrict__ W,
                                            u16* __restrict__ Wt,
                                            int K, int N) {
  __shared__ u16 T[64][72];
  const int n0 = blockIdx.x * 64, k0 = blockIdx.y * 64;
  const int tid = threadIdx.x;
  const int r = tid >> 4, c4 = (tid & 15) * 4;
  const bool vec = ((N & 3) == 0);
#pragma unroll
  for (int it = 0; it < 4; ++it) {
    int k = k0 + r + it * 16;
    int n = n0 + c4;
    float4 v;
    if (vec && (n + 3 < N)) {
      v = *(const float4*)&W[(size_t)k * N + n];
    } else {
      v.x = (n + 0 < N) ? W[(size_t)k * N + n + 0] : 0.f;
      v.y = (n + 1 < N) ? W[(size_t)k * N + n + 1] : 0.f;
      v.z = (n + 2 < N) ? W[(size_t)k * N + n + 2] : 0.f;
      v.w = (n + 3 < N) ? W[(size_t)k * N + n + 3] : 0.f;
    }
    T[c4 + 0][r + it * 16] = f2bf(v.x);
    T[c4 + 1][r + it * 16] = f2bf(v.y);
    T[c4 + 2][r + it * 16] = f2bf(v.z);
    T[c4 + 3][r + it * 16] = f2bf(v.w);
  }
  __syncthreads();
  const int rr = tid >> 3, cc = (tid & 7) * 8;
#pragma unroll
  for (int jt = 0; jt < 2; ++jt) {
    int n = rr + jt * 32;
    *(uint4*)&Wt[(size_t)(n0 + n) * K + k0 + cc] = *(const uint4*)&T[n][cc];
  }
}

// ---------------- GEMM: C[M=4096,N] (op)= A_bf16[M,K](lda) @ Bt_bf16[N,K]^T ----------------
// EPI: 0 = store bf16, 1 = store f32, 2 = add into f32 (atomic when NS>1)
template <int EPI, int NS>
__global__ __launch_bounds__(256) void k_gemm(const u16* __restrict__ A,
                                              const u16* __restrict__ Bt,
                                              void* __restrict__ Cp,
                                              int N, int K, int lda) {
  __shared__ u16 As[128 * 32];
  __shared__ u16 Bs[128 * 32];
  const int bm = blockIdx.y * 128, bn = blockIdx.x * 128;
  const int tid = threadIdx.x;
  const int lane = tid & 63, wid = tid >> 6;
  const int wr = wid >> 1, wc = wid & 1;
  const int l16 = lane & 15, lg = lane >> 4;
  const int srow = tid >> 2, scol = (tid & 3) * 8;
  const u16* Ab = A + (size_t)(bm + srow) * lda + scol;
  const u16* Bb = Bt + (size_t)(bn + srow) * K + scol;
  u16* AsP = As + tid * 8;
  u16* BsP = Bs + tid * 8;
  const int kchunk = K / NS;
  const int kb0 = blockIdx.z * kchunk, kb1 = kb0 + kchunk;
  f32x4 acc[4][4] = {};
  for (int kb = kb0; kb < kb1; kb += 32) {
    __syncthreads();
    gld16(Ab + kb, AsP);
    gld16(Ab + (size_t)64 * lda + kb, AsP + 2048);
    gld16(Bb + kb, BsP);
    gld16(Bb + (size_t)64 * K + kb, BsP + 2048);
    __syncthreads();
    s16x8 af[4], bfr[4];
#pragma unroll
    for (int i = 0; i < 4; ++i)
      af[i] = *(const s16x8*)&As[(64 * wr + 16 * i + l16) * 32 + 8 * lg];
#pragma unroll
    for (int i = 0; i < 4; ++i)
      bfr[i] = *(const s16x8*)&Bs[(64 * wc + 16 * i + l16) * 32 + 8 * lg];
#pragma unroll
    for (int mi = 0; mi < 4; ++mi)
#pragma unroll
      for (int ni = 0; ni < 4; ++ni)
        acc[mi][ni] = mfma16(af[mi], bfr[ni], acc[mi][ni]);
  }
#pragma unroll
  for (int mi = 0; mi < 4; ++mi)
#pragma unroll
    for (int ni = 0; ni < 4; ++ni)
#pragma unroll
      for (int r = 0; r < 4; ++r) {
        int row = bm + 64 * wr + 16 * mi + 4 * lg + r;
        int col = bn + 64 * wc + 16 * ni + l16;
        if (col >= N) continue;
        float val = acc[mi][ni][r];
        size_t off = (size_t)row * N + col;
        if (EPI == 0)      ((u16*)Cp)[off] = f2bf(val);
        else if (EPI == 1) ((float*)Cp)[off] = val;
        else if (NS == 1)  ((float*)Cp)[off] += val;
        else               unsafeAtomicAdd((float*)Cp + off, val);
      }
}

// ---------------- RoPE in-place on bf16, row stride 2048 (fused qkv buf) ----------------
template <int HEADS>
__global__ void k_rope(u16* __restrict__ buf) {
  int idx = blockIdx.x * 256 + threadIdx.x;
  if (idx >= C_NTOK * HEADS * 32) return;
  int i = idx & 31;
  int h = (idx >> 5) % HEADS;
  int t = idx / (32 * HEADS);
  int pos = t & (C_S - 1);
  float inv = expf(-(float)(2 * i) * (1.0f / C_HD) * 13.122363377404328f);
  float ang = (float)pos * inv;
  float sv = sinf(ang), cv = cosf(ang);
  u16* pp = buf + (size_t)t * 2048 + h * C_HD + i;
  float x0 = bf2f(pp[0]), x1 = bf2f(pp[32]);
  pp[0]  = f2bf(x0 * cv - x1 * sv);
  pp[32] = f2bf(x1 * cv + x0 * sv);
}

// ---------------- V transpose: qkv v-slice -> [b,kvh,hd,s] ----------------
__global__ void k_vT(const u16* __restrict__ qkv, u16* __restrict__ vt) {
  int idx = blockIdx.x * 256 + threadIdx.x;
  if (idx >= C_B * C_NKVH * C_HD * C_S) return;
  int s   = idx & (C_S - 1);
  int hd  = (idx >> 11) & (C_HD - 1);
  int kvh = (idx >> 17) & (C_NKVH - 1);
  int b   = idx >> 20;
  vt[idx] = qkv[((size_t)b * C_S + s) * 2048 + 1536 + kvh * C_HD + hd];
}

// ---------------- flash attention, split-KV partials ----------------
// grid (128 qt, NH, B*2); blockIdx.z = b*2+split. Each wave: 16 q-rows, half the
// KV tiles. Emits unnormalized accO (f32), m, lsum. Swapped-QK in-register softmax.
__global__ __launch_bounds__(64) void k_attn(const u16* __restrict__ qkv,
                                             const u16* __restrict__ vt,
                                             const float* __restrict__ bias,
                                             float* __restrict__ pO,
                                             float2* __restrict__ pml) {
  const int qt = blockIdx.x, h = blockIdx.y;
  const int b = blockIdx.z >> 1, split = blockIdx.z & 1;
  const int kvh = h >> 1;
  const int lane = threadIdx.x;
  const int l16 = lane & 15, lg = lane >> 4;
  __shared__ u16 P[16][72];
  const float* biasb = bias + b * C_S;
  const u16* kbase = qkv + (size_t)b * C_S * 2048 + 1024 + kvh * C_HD + 8 * lg;
  const u16* vbase = vt + ((size_t)(b * C_NKVH + kvh) * C_HD + l16) * C_S + 8 * lg;
  const int q0 = qt * 16;
  const int qrow = q0 + l16;
  const int T = (q0 + 16 + 63) / 64;                  // total 64-key tiles
  const int t0 = split ? (T + 1) / 2 : 0;
  const int t1 = split ? T : (T + 1) / 2;
  const u16* qbase = qkv + (size_t)(b * C_S + qrow) * 2048 + h * C_HD + 8 * lg;
  s16x8 qf0 = *(const s16x8*)qbase;
  s16x8 qf1 = *(const s16x8*)(qbase + 32);
  float m = -1e30f, lsum = 0.f;
  f32x4 accO[4];
#pragma unroll
  for (int f = 0; f < 4; ++f) accO[f] = (f32x4){0.f, 0.f, 0.f, 0.f};
  for (int t = t0; t < t1; ++t) {
    const int kt = t * 64;
    f32x4 sc[4];
#pragma unroll
    for (int jt = 0; jt < 4; ++jt) sc[jt] = (f32x4){0.f, 0.f, 0.f, 0.f};
#pragma unroll
    for (int jt = 0; jt < 4; ++jt) {
      const u16* kp = kbase + (size_t)(kt + 16 * jt + l16) * 2048;
      s16x8 k0 = *(const s16x8*)kp;
      s16x8 k1 = *(const s16x8*)(kp + 32);
      sc[jt] = mfma16(k0, qf0, sc[jt]);
      sc[jt] = mfma16(k1, qf1, sc[jt]);
    }
    float mt = -1e30f;
#pragma unroll
    for (int jt = 0; jt < 4; ++jt) {
      float4 bb = *(const float4*)&biasb[kt + 16 * jt + 4 * lg];
      int kv0 = kt + 16 * jt + 4 * lg;
      const float* bp = (const float*)&bb;
#pragma unroll
      for (int r = 0; r < 4; ++r) {
        float val = sc[jt][r] * 0.125f + bp[r];
        if (kv0 + r > qrow) val = -1e30f;
        sc[jt][r] = val;
        mt = fmaxf(mt, val);
      }
    }
    mt = fmaxf(mt, __shfl_xor(mt, 16, 64));
    mt = fmaxf(mt, __shfl_xor(mt, 32, 64));
    float mn = fmaxf(m, mt);
    float cc = __expf(m - mn);
    m = mn;
    float ps = 0.f;
#pragma unroll
    for (int jt = 0; jt < 4; ++jt)
#pragma unroll
      for (int r = 0; r < 4; ++r) {
        float pv = __expf(sc[jt][r] - m);
        sc[jt][r] = pv;
        ps += pv;
      }
    ps += __shfl_xor(ps, 16, 64);
    ps += __shfl_xor(ps, 32, 64);
    lsum = lsum * cc + ps;
#pragma unroll
    for (int f = 0; f < 4; ++f)
#pragma unroll
      for (int r = 0; r < 4; ++r) accO[f][r] *= cc;
#pragma unroll
    for (int jt = 0; jt < 4; ++jt) {
      uint2 w;
      w.x = (u32)f2bf(sc[jt][0]) | ((u32)f2bf(sc[jt][1]) << 16);
      w.y = (u32)f2bf(sc[jt][2]) | ((u32)f2bf(sc[jt][3]) << 16);
      *(uint2*)&P[l16][16 * jt + 4 * lg] = w;
    }
    __syncthreads();
    s16x8 pf0 = *(const s16x8*)&P[l16][8 * lg];
    s16x8 pf1 = *(const s16x8*)&P[l16][32 + 8 * lg];
#pragma unroll
    for (int f = 0; f < 4; ++f) {
      const u16* vb = vbase + (size_t)(16 * f) * C_S + kt;
      s16x8 vf0 = *(const s16x8*)vb;
      s16x8 vf1 = *(const s16x8*)(vb + 32);
      accO[f] = mfma16(vf0, pf0, accO[f]);
      accO[f] = mfma16(vf1, pf1, accO[f]);
    }
    __syncthreads();
  }
  // partial store: pO[split][tok][h*64+d] (f32), pml[split][tok][h] = (m, lsum)
  const size_t tok = (size_t)b * C_S + qrow;
  float* po = pO + ((size_t)split * C_NTOK + tok) * 1024 + h * 64 + 4 * lg;
#pragma unroll
  for (int f = 0; f < 4; ++f) {
    float4 w;
    w.x = accO[f][0]; w.y = accO[f][1]; w.z = accO[f][2]; w.w = accO[f][3];
    *(float4*)(po + 16 * f) = w;
  }
  if (lg == 0) pml[((size_t)split * C_NTOK + tok) * C_NH + h] = make_float2(m, lsum);
}

// ---------------- merge split-KV partials -> bf16 O ----------------
__global__ __launch_bounds__(256) void k_attn_merge(const float* __restrict__ pO,
                                                    const float2* __restrict__ pml,
                                                    u16* __restrict__ o) {
  size_t idx = (size_t)blockIdx.x * 256 + threadIdx.x;   // 1M threads, 4 elems each
  size_t pos = idx * 4;
  size_t tok = pos >> 10;
  int h = (int)((pos >> 6) & 15);
  float4 o1 = *(const float4*)(pO + pos);
  float4 o2 = *(const float4*)(pO + (size_t)C_NTOK * 1024 + pos);
  float2 ml1 = pml[tok * C_NH + h];
  float2 ml2 = pml[(size_t)C_NTOK * C_NH + tok * C_NH + h];
  float M = fmaxf(ml1.x, ml2.x);
  float w1 = __expf(ml1.x - M), w2 = __expf(ml2.x - M);
  float dn = 1.0f / (ml1.y * w1 + ml2.y * w2);
  float r0 = (o1.x * w1 + o2.x * w2) * dn;
  float r1 = (o1.y * w1 + o2.y * w2) * dn;
  float r2 = (o1.z * w1 + o2.z * w2) * dn;
  float r3 = (o1.w * w1 + o2.w * w2) * dn;
  uint2 w;
  w.x = (u32)f2bf(r0) | ((u32)f2bf(r1) << 16);
  w.y = (u32)f2bf(r2) | ((u32)f2bf(r3) << 16);
  *(uint2*)(o + pos) = w;
}

// ---------------- silu(g)*u -> g in place; halves of gu[4096][8192] ----------------
__global__ void k_silumul(u16* __restrict__ gu) {
  int idx = blockIdx.x * 256 + threadIdx.x;
  int row = idx >> 9;
  int c8 = (idx & 511) * 8;
  u16* g = gu + (size_t)row * 8192 + c8;
  const u16* u = g + 4096;
  uint4 gv = *(const uint4*)g;
  uint4 uv = *(const uint4*)u;
  u32* gp = (u32*)&gv;
  u32* up = (u32*)&uv;
  u32 go[4];
#pragma unroll
  for (int j = 0; j < 4; ++j) {
    float g0 = bf2f((u16)(gp[j] & 0xffff)), g1 = bf2f((u16)(gp[j] >> 16));
    float u0 = bf2f((u16)(up[j] & 0xffff)), u1 = bf2f((u16)(up[j] >> 16));
    float s0 = g0 / (1.0f + __expf(-g0));
    float s1 = g1 / (1.0f + __expf(-g1));
    go[j] = (u32)f2bf(s0 * u0) | ((u32)f2bf(s1 * u1) << 16);
  }
  *(uint4*)g = *(uint4*)go;
}

extern "C" void kernel_launch(void* const* d_in, const int* in_sizes, int n_in,
                              void* d_out, int out_size, void* d_ws, size_t ws_size,
                              hipStream_t stream) {
  const int*   ids  = (const int*)d_in[0];
  const float* emb  = (const float*)d_in[1];
  const float* Wq   = (const float*)d_in[2];
  const float* Wk   = (const float*)d_in[3];
  const float* Wv   = (const float*)d_in[4];
  const float* Wo   = (const float*)d_in[5];
  const float* Wg   = (const float*)d_in[6];
  const float* Wu   = (const float*)d_in[7];
  const float* Wd   = (const float*)d_in[8];
  const float* anw  = (const float*)d_in[9];
  const float* fnw  = (const float*)d_in[10];
  const float* finw = (const float*)d_in[11];
  const float* lmh  = (const float*)d_in[12];

  char* p = (char*)d_ws;
  float* x  = (float*)p; p += (size_t)C_NTOK * C_DIM * 4;
  u16* hn   = (u16*)p;   p += (size_t)C_NTOK * C_DIM * 2;
  u16* qkv  = (u16*)p;   p += (size_t)C_NTOK * 2048 * 2;
  u16* vtb  = (u16*)p;   p += (size_t)C_NTOK * C_NKVH * C_HD * 2;
  u16* ao   = (u16*)p;   p += (size_t)C_NTOK * C_NH * C_HD * 2;
  u16* gu   = (u16*)p;   p += (size_t)C_NTOK * 2 * C_FF * 2;   // 64MB; attn partials alias here
  u16* wT   = (u16*)p;   p += (size_t)8192 * 1024 * 2;
  float* bias = (float*)p;

  // attn partials alias the (then unused) gu region: 32MB pO + 1MB pml
  float*  pO  = (float*)gu;
  float2* pml = (float2*)((char*)gu + (size_t)2 * C_NTOK * 1024 * 4);

  k_embed<<<C_NTOK, 256, 0, stream>>>(ids, emb, x);
  k_bias<<<C_NTOK / 256, 256, 0, stream>>>(ids, bias);

  for (int l = 0; l < C_NL; ++l) {
    k_rmsnorm<<<C_NTOK, 256, 0, stream>>>(x, anw + (size_t)l * C_DIM, hn);
    k_wT<<<dim3(16, 16), 256, 0, stream>>>(Wq + (size_t)l * C_DIM * 1024, wT, C_DIM, 1024);
    k_wT<<<dim3(8, 16), 256, 0, stream>>>(Wk + (size_t)l * C_DIM * 512, wT + (size_t)1024 * C_DIM, C_DIM, 512);
    k_wT<<<dim3(8, 16), 256, 0, stream>>>(Wv + (size_t)l * C_DIM * 512, wT + (size_t)1536 * C_DIM, C_DIM, 512);
    k_gemm<0, 1><<<dim3(16, 32), 256, 0, stream>>>(hn, wT, qkv, 2048, C_DIM, C_DIM);
    k_rope<C_NH><<<C_NTOK * C_NH * 32 / 256, 256, 0, stream>>>(qkv);
    k_rope<C_NKVH><<<C_NTOK * C_NKVH * 32 / 256, 256, 0, stream>>>(qkv + 1024);
    k_vT<<<C_NTOK * C_NKVH * C_HD / 256, 256, 0, stream>>>(qkv, vtb);
    k_attn<<<dim3(C_S / 16, C_NH, C_B * 2), 64, 0, stream>>>(qkv, vtb, bias, pO, pml);
    k_attn_merge<<<C_NTOK * 1024 / 4 / 256, 256, 0, stream>>>(pO, pml, ao);
    k_wT<<<dim3(16, 16), 256, 0, stream>>>(Wo + (size_t)l * 1024 * C_DIM, wT, 1024, C_DIM);
    k_gemm<2, 2><<<dim3(8, 32, 2), 256, 0, stream>>>(ao, wT, x, C_DIM, 1024, 1024);
    k_rmsnorm<<<C_NTOK, 256, 0, stream>>>(x, fnw + (size_t)l * C_DIM, hn);
    k_wT<<<dim3(64, 16), 256, 0, stream>>>(Wg + (size_t)l * C_DIM * C_FF, wT, C_DIM, C_FF);
    k_wT<<<dim3(64, 16), 256, 0, stream>>>(Wu + (size_t)l * C_DIM * C_FF, wT + (size_t)C_FF * C_DIM, C_DIM, C_FF);
    k_gemm<0, 1><<<dim3(64, 32), 256, 0, stream>>>(hn, wT, gu, 8192, C_DIM, C_DIM);
    k_silumul<<<C_NTOK * 512 / 256, 256, 0, stream>>>(gu);
    k_wT<<<dim3(16, 64), 256, 0, stream>>>(Wd + (size_t)l * C_FF * C_DIM, wT, C_FF, C_DIM);
    k_gemm<2, 4><<<dim3(8, 32, 4), 256, 0, stream>>>(gu, wT, x, C_DIM, C_FF, 8192);
  }
  k_rmsnorm<<<C_NTOK, 256, 0, stream>>>(x, finw, hn);
  k_wT<<<dim3(64, 16), 256, 0, stream>>>(lmh, wT, C_DIM, C_V);
  k_gemm<1, 1><<<dim3(32, 32), 256, 0, stream>>>(hn, wT, (float*)d_out, C_V, C_DIM, C_DIM);
}

// Round 6
// 3703.224 us; speedup vs baseline: 1.1352x; 1.1352x over previous
//
#include <hip/hip_runtime.h>

constexpr int C_NTOK = 4096;   // B*S
constexpr int C_DIM  = 1024;
constexpr int C_NL   = 8;
constexpr int C_NH   = 16;
constexpr int C_NKVH = 8;
constexpr int C_FF   = 4096;
constexpr int C_HD   = 64;
constexpr int C_B    = 2;
constexpr int C_S    = 2048;
constexpr int C_V    = 4054;
constexpr int C_PAD  = 4053;

typedef unsigned short u16;
typedef unsigned int   u32;
typedef __attribute__((ext_vector_type(4))) float f32x4;
typedef __attribute__((ext_vector_type(8))) short s16x8;

__device__ __forceinline__ float bf2f(u16 u) {
  u32 i = ((u32)u) << 16; float f; __builtin_memcpy(&f, &i, 4); return f;
}
__device__ __forceinline__ u16 f2bf(float f) {
  u32 i; __builtin_memcpy(&i, &f, 4);
  return (u16)((i + 0x7FFFu + ((i >> 16) & 1u)) >> 16);   // RNE
}
__device__ __forceinline__ f32x4 mfma16(s16x8 a, s16x8 b, f32x4 c) {
  return __builtin_amdgcn_mfma_f32_16x16x32_bf16(a, b, c, 0, 0, 0);
}
__device__ __forceinline__ void gld16(const void* g, void* l) {
  __builtin_amdgcn_global_load_lds((const __attribute__((address_space(1))) unsigned int*)g,
                                   (__attribute__((address_space(3))) unsigned int*)l, 16, 0, 0);
}

// ---------------- embedding gather ----------------
__global__ __launch_bounds__(256) void k_embed(const int* __restrict__ ids,
                                               const float* __restrict__ emb,
                                               float* __restrict__ x) {
  int t = blockIdx.x;
  const float4* src = (const float4*)(emb + (size_t)ids[t] * C_DIM);
  float4* dst = (float4*)(x + (size_t)t * C_DIM);
  dst[threadIdx.x] = src[threadIdx.x];
}

// ---------------- pad-key bias ----------------
__global__ void k_bias(const int* __restrict__ ids, float* __restrict__ bias) {
  int i = blockIdx.x * 256 + threadIdx.x;
  if (i < C_NTOK) bias[i] = (ids[i] == C_PAD) ? -1e30f : 0.0f;
}

// ---------------- rmsnorm: fp32 row -> bf16 row ----------------
__global__ __launch_bounds__(256) void k_rmsnorm(const float* __restrict__ x,
                                                 const float* __restrict__ w,
                                                 u16* __restrict__ out) {
  int row = blockIdx.x, tid = threadIdx.x;
  float4 v = ((const float4*)(x + (size_t)row * C_DIM))[tid];
  float ss = v.x * v.x + v.y * v.y + v.z * v.z + v.w * v.w;
#pragma unroll
  for (int d = 1; d < 64; d <<= 1) ss += __shfl_xor(ss, d, 64);
  __shared__ float sm[4];
  if ((tid & 63) == 0) sm[tid >> 6] = ss;
  __syncthreads();
  float tot = sm[0] + sm[1] + sm[2] + sm[3];
  float rs = 1.0f / sqrtf(tot * (1.0f / C_DIM) + 1e-5f);
  float4 wv = ((const float4*)w)[tid];
  uint2 o;
  o.x = (u32)f2bf(v.x * rs * wv.x) | ((u32)f2bf(v.y * rs * wv.y) << 16);
  o.y = (u32)f2bf(v.z * rs * wv.z) | ((u32)f2bf(v.w * rs * wv.w) << 16);
  ((uint2*)(out + (size_t)row * C_DIM))[tid] = o;
}

// ---------------- weight transpose-convert: W[K,N] f32 -> Wt[Npad,K] bf16 ----------------
__global__ __launch_bounds__(256) void k_wT(const float* __restrict__ W,
                                            u16* __restrict__ Wt,
                                            int K, int N) {
  __shared__ u16 T[64][72];
  const int n0 = blockIdx.x * 64, k0 = blockIdx.y * 64;
  const int tid = threadIdx.x;
  const int r = tid >> 4, c4 = (tid & 15) * 4;
  const bool vec = ((N & 3) == 0);
#pragma unroll
  for (int it = 0; it < 4; ++it) {
    int k = k0 + r + it * 16;
    int n = n0 + c4;
    float4 v;
    if (vec && (n + 3 < N)) {
      v = *(const float4*)&W[(size_t)k * N + n];
    } else {
      v.x = (n + 0 < N) ? W[(size_t)k * N + n + 0] : 0.f;
      v.y = (n + 1 < N) ? W[(size_t)k * N + n + 1] : 0.f;
      v.z = (n + 2 < N) ? W[(size_t)k * N + n + 2] : 0.f;
      v.w = (n + 3 < N) ? W[(size_t)k * N + n + 3] : 0.f;
    }
    T[c4 + 0][r + it * 16] = f2bf(v.x);
    T[c4 + 1][r + it * 16] = f2bf(v.y);
    T[c4 + 2][r + it * 16] = f2bf(v.z);
    T[c4 + 3][r + it * 16] = f2bf(v.w);
  }
  __syncthreads();
  const int rr = tid >> 3, cc = (tid & 7) * 8;
#pragma unroll
  for (int jt = 0; jt < 2; ++jt) {
    int n = rr + jt * 32;
    *(uint4*)&Wt[(size_t)(n0 + n) * K + k0 + cc] = *(const uint4*)&T[n][cc];
  }
}

// ---------------- GEMM: C[M=4096,N] (op)= A_bf16[M,K](lda) @ Bt_bf16[N,K]^T ----------------
// EPI: 0 = store bf16, 1 = store f32, 2 = add into f32 (atomic when NS>1)
// 128x128 tile, BK=32, 4 waves, double-buffered LDS (2-phase prefetch), XCD swizzle.
template <int EPI, int NS>
__global__ __launch_bounds__(256) void k_gemm(const u16* __restrict__ A,
                                              const u16* __restrict__ Bt,
                                              void* __restrict__ Cp,
                                              int N, int K, int lda) {
  __shared__ u16 As[2][128 * 32];
  __shared__ u16 Bs[2][128 * 32];
  // XCD-aware bijective swizzle (all launches have nwg % 8 == 0)
  const int nx = gridDim.x;
  int lin = blockIdx.y * nx + blockIdx.x;
  const int nwg = nx * gridDim.y;
  if ((nwg & 7) == 0) lin = (lin & 7) * (nwg >> 3) + (lin >> 3);
  const int bm = (lin / nx) * 128, bn = (lin % nx) * 128;
  const int tid = threadIdx.x;
  const int lane = tid & 63, wid = tid >> 6;
  const int wr = wid >> 1, wc = wid & 1;
  const int l16 = lane & 15, lg = lane >> 4;
  const int srow = tid >> 2, scol = (tid & 3) * 8;
  const u16* Ab = A + (size_t)(bm + srow) * lda + scol;
  const u16* Bb = Bt + (size_t)(bn + srow) * K + scol;
  const int kchunk = K / NS;
  const int kb0 = blockIdx.z * kchunk, kb1 = kb0 + kchunk;
  f32x4 acc[4][4] = {};
  // prologue: stage kb0 into buf 0
  {
    u16* ad = &As[0][tid * 8];
    u16* bd = &Bs[0][tid * 8];
    gld16(Ab + kb0, ad);
    gld16(Ab + (size_t)64 * lda + kb0, ad + 2048);
    gld16(Bb + kb0, bd);
    gld16(Bb + (size_t)64 * K + kb0, bd + 2048);
  }
  __syncthreads();
  int cur = 0;
  for (int kb = kb0; kb < kb1; kb += 32) {
    const int nkb = kb + 32;
    if (nkb < kb1) {   // prefetch next tile into the other buffer
      u16* ad = &As[cur ^ 1][tid * 8];
      u16* bd = &Bs[cur ^ 1][tid * 8];
      gld16(Ab + nkb, ad);
      gld16(Ab + (size_t)64 * lda + nkb, ad + 2048);
      gld16(Bb + nkb, bd);
      gld16(Bb + (size_t)64 * K + nkb, bd + 2048);
    }
    s16x8 af[4], bfr[4];
#pragma unroll
    for (int i = 0; i < 4; ++i)
      af[i] = *(const s16x8*)&As[cur][(64 * wr + 16 * i + l16) * 32 + 8 * lg];
#pragma unroll
    for (int i = 0; i < 4; ++i)
      bfr[i] = *(const s16x8*)&Bs[cur][(64 * wc + 16 * i + l16) * 32 + 8 * lg];
#pragma unroll
    for (int mi = 0; mi < 4; ++mi)
#pragma unroll
      for (int ni = 0; ni < 4; ++ni)
        acc[mi][ni] = mfma16(af[mi], bfr[ni], acc[mi][ni]);
    __syncthreads();   // drains prefetch vmcnt + all reads of buf[cur] done
    cur ^= 1;
  }
  // C/D layout: col=lane&15, row=4*(lane>>4)+reg
#pragma unroll
  for (int mi = 0; mi < 4; ++mi)
#pragma unroll
    for (int ni = 0; ni < 4; ++ni)
#pragma unroll
      for (int r = 0; r < 4; ++r) {
        int row = bm + 64 * wr + 16 * mi + 4 * lg + r;
        int col = bn + 64 * wc + 16 * ni + l16;
        if (col >= N) continue;
        float val = acc[mi][ni][r];
        size_t off = (size_t)row * N + col;
        if (EPI == 0)      ((u16*)Cp)[off] = f2bf(val);
        else if (EPI == 1) ((float*)Cp)[off] = val;
        else if (NS == 1)  ((float*)Cp)[off] += val;
        else               unsafeAtomicAdd((float*)Cp + off, val);
      }
}

// ---------------- RoPE in-place on bf16, row stride 2048 (fused qkv buf) ----------------
template <int HEADS>
__global__ void k_rope(u16* __restrict__ buf) {
  int idx = blockIdx.x * 256 + threadIdx.x;
  if (idx >= C_NTOK * HEADS * 32) return;
  int i = idx & 31;
  int h = (idx >> 5) % HEADS;
  int t = idx / (32 * HEADS);
  int pos = t & (C_S - 1);
  float inv = expf(-(float)(2 * i) * (1.0f / C_HD) * 13.122363377404328f);
  float ang = (float)pos * inv;
  float sv = sinf(ang), cv = cosf(ang);
  u16* pp = buf + (size_t)t * 2048 + h * C_HD + i;
  float x0 = bf2f(pp[0]), x1 = bf2f(pp[32]);
  pp[0]  = f2bf(x0 * cv - x1 * sv);
  pp[32] = f2bf(x1 * cv + x0 * sv);
}

// ---------------- V transpose: qkv v-slice -> [b,kvh,hd,s] ----------------
__global__ void k_vT(const u16* __restrict__ qkv, u16* __restrict__ vt) {
  int idx = blockIdx.x * 256 + threadIdx.x;
  if (idx >= C_B * C_NKVH * C_HD * C_S) return;
  int s   = idx & (C_S - 1);
  int hd  = (idx >> 11) & (C_HD - 1);
  int kvh = (idx >> 17) & (C_NKVH - 1);
  int b   = idx >> 20;
  vt[idx] = qkv[((size_t)b * C_S + s) * 2048 + 1536 + kvh * C_HD + hd];
}

// ---------------- flash attention: swapped-QK, reg-prefetched K/V, no vmcnt drains ----
// 1 wave per 16 q-rows; block handles q-tiles (qp, 127-qp) for load balance.
// QK^T = mfma(K, Q): lane(l16,lg) reg r of sc[jt] = S[q=q0+l16][key=kt+16jt+4lg+r].
// PV = mfma(V^T, P): accO[f][r] = O[q=l16][d=16f+4lg+r]. Softmax state scalar per lane.
// Loop-carried K/V fragment prefetch: kf for tile t+1 loads right after QK(t),
// vf for t+1 right after PV(t). P-bounce syncs via lgkmcnt(0)+sched_barrier only
// (single-wave block; no vmcnt drain -> prefetch stays in flight).
__global__ __launch_bounds__(64) void k_attn(const u16* __restrict__ qkv,
                                             const u16* __restrict__ vt,
                                             const float* __restrict__ bias,
                                             u16* __restrict__ o) {
  const int qp = blockIdx.x, h = blockIdx.y, b = blockIdx.z;
  const int kvh = h >> 1;
  const int lane = threadIdx.x;
  const int l16 = lane & 15, lg = lane >> 4;
  __shared__ u16 P[16][72];
  const float* biasb = bias + b * C_S;
  const u16* kbase = qkv + (size_t)b * C_S * 2048 + 1024 + kvh * C_HD + 8 * lg;
  const u16* vbase = vt + ((size_t)(b * C_NKVH + kvh) * C_HD + l16) * C_S + 8 * lg;
#pragma unroll
  for (int half = 0; half < 2; ++half) {
    const int qt = half ? (127 - qp) : qp;
    const int q0 = qt * 16;
    const int qrow = q0 + l16;
    const u16* qbase = qkv + (size_t)(b * C_S + qrow) * 2048 + h * C_HD + 8 * lg;
    s16x8 qf0 = *(const s16x8*)qbase;
    s16x8 qf1 = *(const s16x8*)(qbase + 32);
    float m = -1e30f, lsum = 0.f;
    f32x4 accO[4];
#pragma unroll
    for (int f = 0; f < 4; ++f) accO[f] = (f32x4){0.f, 0.f, 0.f, 0.f};
    const int nt = (q0 + 16 + 63) >> 6;
    s16x8 kf[8], vf[8];
#pragma unroll
    for (int jt = 0; jt < 4; ++jt) {
      const u16* kp = kbase + (size_t)(16 * jt + l16) * 2048;
      kf[2 * jt]     = *(const s16x8*)kp;
      kf[2 * jt + 1] = *(const s16x8*)(kp + 32);
    }
#pragma unroll
    for (int f = 0; f < 4; ++f) {
      const u16* vb = vbase + (size_t)(16 * f) * C_S;
      vf[2 * f]     = *(const s16x8*)vb;
      vf[2 * f + 1] = *(const s16x8*)(vb + 32);
    }
    for (int t = 0; t < nt; ++t) {
      const int kt = t * 64;
      f32x4 sc[4];
#pragma unroll
      for (int jt = 0; jt < 4; ++jt) sc[jt] = (f32x4){0.f, 0.f, 0.f, 0.f};
#pragma unroll
      for (int jt = 0; jt < 4; ++jt) {
        sc[jt] = mfma16(kf[2 * jt],     qf0, sc[jt]);
        sc[jt] = mfma16(kf[2 * jt + 1], qf1, sc[jt]);
      }
      if (t + 1 < nt) {   // prefetch K for next tile (kf consumed above)
#pragma unroll
        for (int jt = 0; jt < 4; ++jt) {
          const u16* kp = kbase + (size_t)(kt + 64 + 16 * jt + l16) * 2048;
          kf[2 * jt]     = *(const s16x8*)kp;
          kf[2 * jt + 1] = *(const s16x8*)(kp + 32);
        }
      }
      float mt = -1e30f;
#pragma unroll
      for (int jt = 0; jt < 4; ++jt) {
        float4 bb = *(const float4*)&biasb[kt + 16 * jt + 4 * lg];
        int kv0 = kt + 16 * jt + 4 * lg;
        const float* bp = (const float*)&bb;
#pragma unroll
        for (int r = 0; r < 4; ++r) {
          float val = sc[jt][r] * 0.125f + bp[r];
          if (kv0 + r > qrow) val = -1e30f;
          sc[jt][r] = val;
          mt = fmaxf(mt, val);
        }
      }
      mt = fmaxf(mt, __shfl_xor(mt, 16, 64));
      mt = fmaxf(mt, __shfl_xor(mt, 32, 64));
      float mn = fmaxf(m, mt);
      float cc = __expf(m - mn);
      m = mn;
      float ps = 0.f;
#pragma unroll
      for (int jt = 0; jt < 4; ++jt)
#pragma unroll
        for (int r = 0; r < 4; ++r) {
          float pv = __expf(sc[jt][r] - m);
          sc[jt][r] = pv;
          ps += pv;
        }
      ps += __shfl_xor(ps, 16, 64);
      ps += __shfl_xor(ps, 32, 64);
      lsum = lsum * cc + ps;
#pragma unroll
      for (int f = 0; f < 4; ++f)
#pragma unroll
        for (int r = 0; r < 4; ++r) accO[f][r] *= cc;
      // P[q=l16][key_rel=16jt+4lg+r] as packed 8B writes
#pragma unroll
      for (int jt = 0; jt < 4; ++jt) {
        uint2 w;
        w.x = (u32)f2bf(sc[jt][0]) | ((u32)f2bf(sc[jt][1]) << 16);
        w.y = (u32)f2bf(sc[jt][2]) | ((u32)f2bf(sc[jt][3]) << 16);
        *(uint2*)&P[l16][16 * jt + 4 * lg] = w;
      }
      asm volatile("s_waitcnt lgkmcnt(0)" ::: "memory");   // DS writes retired
      __builtin_amdgcn_sched_barrier(0);                   // rule 18: pin MFMA below
      s16x8 pf0 = *(const s16x8*)&P[l16][8 * lg];
      s16x8 pf1 = *(const s16x8*)&P[l16][32 + 8 * lg];
#pragma unroll
      for (int f = 0; f < 4; ++f) {
        accO[f] = mfma16(vf[2 * f],     pf0, accO[f]);
        accO[f] = mfma16(vf[2 * f + 1], pf1, accO[f]);
      }
      if (t + 1 < nt) {   // prefetch V for next tile (vf consumed above)
#pragma unroll
        for (int f = 0; f < 4; ++f) {
          const u16* vb = vbase + (size_t)(16 * f) * C_S + kt + 64;
          vf[2 * f]     = *(const s16x8*)vb;
          vf[2 * f + 1] = *(const s16x8*)(vb + 32);
        }
      }
    }
    float linv = 1.0f / lsum;
    u16* ob = o + ((size_t)(b * C_S + qrow)) * 1024 + h * C_HD + 4 * lg;
#pragma unroll
    for (int f = 0; f < 4; ++f) {
      uint2 w;
      w.x = (u32)f2bf(accO[f][0] * linv) | ((u32)f2bf(accO[f][1] * linv) << 16);
      w.y = (u32)f2bf(accO[f][2] * linv) | ((u32)f2bf(accO[f][3] * linv) << 16);
      *(uint2*)(ob + 16 * f) = w;
    }
  }
}

// ---------------- silu(g)*u -> g in place; halves of gu[4096][8192] ----------------
__global__ void k_silumul(u16* __restrict__ gu) {
  int idx = blockIdx.x * 256 + threadIdx.x;
  int row = idx >> 9;
  int c8 = (idx & 511) * 8;
  u16* g = gu + (size_t)row * 8192 + c8;
  const u16* u = g + 4096;
  uint4 gv = *(const uint4*)g;
  uint4 uv = *(const uint4*)u;
  u32* gp = (u32*)&gv;
  u32* up = (u32*)&uv;
  u32 go[4];
#pragma unroll
  for (int j = 0; j < 4; ++j) {
    float g0 = bf2f((u16)(gp[j] & 0xffff)), g1 = bf2f((u16)(gp[j] >> 16));
    float u0 = bf2f((u16)(up[j] & 0xffff)), u1 = bf2f((u16)(up[j] >> 16));
    float s0 = g0 / (1.0f + __expf(-g0));
    float s1 = g1 / (1.0f + __expf(-g1));
    go[j] = (u32)f2bf(s0 * u0) | ((u32)f2bf(s1 * u1) << 16);
  }
  *(uint4*)g = *(uint4*)go;
}

extern "C" void kernel_launch(void* const* d_in, const int* in_sizes, int n_in,
                              void* d_out, int out_size, void* d_ws, size_t ws_size,
                              hipStream_t stream) {
  const int*   ids  = (const int*)d_in[0];
  const float* emb  = (const float*)d_in[1];
  const float* Wq   = (const float*)d_in[2];
  const float* Wk   = (const float*)d_in[3];
  const float* Wv   = (const float*)d_in[4];
  const float* Wo   = (const float*)d_in[5];
  const float* Wg   = (const float*)d_in[6];
  const float* Wu   = (const float*)d_in[7];
  const float* Wd   = (const float*)d_in[8];
  const float* anw  = (const float*)d_in[9];
  const float* fnw  = (const float*)d_in[10];
  const float* finw = (const float*)d_in[11];
  const float* lmh  = (const float*)d_in[12];

  char* p = (char*)d_ws;
  float* x  = (float*)p; p += (size_t)C_NTOK * C_DIM * 4;
  u16* hn   = (u16*)p;   p += (size_t)C_NTOK * C_DIM * 2;
  u16* qkv  = (u16*)p;   p += (size_t)C_NTOK * 2048 * 2;
  u16* vtb  = (u16*)p;   p += (size_t)C_NTOK * C_NKVH * C_HD * 2;
  u16* ao   = (u16*)p;   p += (size_t)C_NTOK * C_NH * C_HD * 2;
  u16* gu   = (u16*)p;   p += (size_t)C_NTOK * 2 * C_FF * 2;
  u16* wT   = (u16*)p;   p += (size_t)8192 * 1024 * 2;
  float* bias = (float*)p;

  k_embed<<<C_NTOK, 256, 0, stream>>>(ids, emb, x);
  k_bias<<<C_NTOK / 256, 256, 0, stream>>>(ids, bias);

  for (int l = 0; l < C_NL; ++l) {
    k_rmsnorm<<<C_NTOK, 256, 0, stream>>>(x, anw + (size_t)l * C_DIM, hn);
    k_wT<<<dim3(16, 16), 256, 0, stream>>>(Wq + (size_t)l * C_DIM * 1024, wT, C_DIM, 1024);
    k_wT<<<dim3(8, 16), 256, 0, stream>>>(Wk + (size_t)l * C_DIM * 512, wT + (size_t)1024 * C_DIM, C_DIM, 512);
    k_wT<<<dim3(8, 16), 256, 0, stream>>>(Wv + (size_t)l * C_DIM * 512, wT + (size_t)1536 * C_DIM, C_DIM, 512);
    k_gemm<0, 1><<<dim3(16, 32), 256, 0, stream>>>(hn, wT, qkv, 2048, C_DIM, C_DIM);
    k_rope<C_NH><<<C_NTOK * C_NH * 32 / 256, 256, 0, stream>>>(qkv);
    k_rope<C_NKVH><<<C_NTOK * C_NKVH * 32 / 256, 256, 0, stream>>>(qkv + 1024);
    k_vT<<<C_NTOK * C_NKVH * C_HD / 256, 256, 0, stream>>>(qkv, vtb);
    k_attn<<<dim3(64, C_NH, C_B), 64, 0, stream>>>(qkv, vtb, bias, ao);
    k_wT<<<dim3(16, 16), 256, 0, stream>>>(Wo + (size_t)l * 1024 * C_DIM, wT, 1024, C_DIM);
    k_gemm<2, 2><<<dim3(8, 32, 2), 256, 0, stream>>>(ao, wT, x, C_DIM, 1024, 1024);
    k_rmsnorm<<<C_NTOK, 256, 0, stream>>>(x, fnw + (size_t)l * C_DIM, hn);
    k_wT<<<dim3(64, 16), 256, 0, stream>>>(Wg + (size_t)l * C_DIM * C_FF, wT, C_DIM, C_FF);
    k_wT<<<dim3(64, 16), 256, 0, stream>>>(Wu + (size_t)l * C_DIM * C_FF, wT + (size_t)C_FF * C_DIM, C_DIM, C_FF);
    k_gemm<0, 1><<<dim3(64, 32), 256, 0, stream>>>(hn, wT, gu, 8192, C_DIM, C_DIM);
    k_silumul<<<C_NTOK * 512 / 256, 256, 0, stream>>>(gu);
    k_wT<<<dim3(16, 64), 256, 0, stream>>>(Wd + (size_t)l * C_FF * C_DIM, wT, C_FF, C_DIM);
    k_gemm<2, 4><<<dim3(8, 32, 4), 256, 0, stream>>>(gu, wT, x, C_DIM, C_FF, 8192);
  }
  k_rmsnorm<<<C_NTOK, 256, 0, stream>>>(x, finw, hn);
  k_wT<<<dim3(64, 16), 256, 0, stream>>>(lmh, wT, C_DIM, C_V);
  k_gemm<1, 1><<<dim3(32, 32), 256, 0, stream>>>(hn, wT, (float*)d_out, C_V, C_DIM, C_DIM);
}